// Round 1
// baseline (185.450 us; speedup 1.0000x reference)
//
#include <hip/hip_runtime.h>
#include <hip/hip_bf16.h>

// out[o,i,h,w] = sum_k weights[o,i,k] * x[k,h,w]
// weights: (2048, 2048, 3) fp32   x: (3, 3, 3) fp32   out: (2048, 2048, 3, 3) fp32
//
// Memory-bound: 50.3 MB read + 151 MB write, ~190 MFLOP. Target ~32 us @ 6.3 TB/s.

#define PAIRS_PER_BLOCK 256
#define OUT_FLOATS_PER_BLOCK (PAIRS_PER_BLOCK * 9)   // 2304 floats = 9216 B, 16B-aligned base

__global__ __launch_bounds__(256) void gf_kernel(const float* __restrict__ x,
                                                 const float* __restrict__ w,
                                                 float* __restrict__ out) {
    __shared__ __align__(16) float so[OUT_FLOATS_PER_BLOCK];

    const int t = threadIdx.x;
    const unsigned pairBase = blockIdx.x * PAIRS_PER_BLOCK;
    const unsigned p = pairBase + t;

    // 3 contiguous weight floats per thread; lanes stride 12 B -> coalesced.
    const float w0 = w[p * 3 + 0];
    const float w1 = w[p * 3 + 1];
    const float w2 = w[p * 3 + 2];

    // x indices are compile-time constants and wave-uniform -> scalar loads (s_load),
    // served by the constant cache; negligible traffic.
#pragma unroll
    for (int hw = 0; hw < 9; ++hw) {
        // LDS write stride 9 floats: gcd(9,32)=1 -> 2 lanes/bank (free on CDNA4).
        so[t * 9 + hw] = w0 * x[hw] + w1 * x[9 + hw] + w2 * x[18 + hw];
    }

    __syncthreads();

    // Cooperative flush: 576 float4 stores, fully coalesced & 16B-aligned.
    float4* __restrict__ outv = (float4*)(out + (size_t)pairBase * 9);
    const float4* __restrict__ sov = (const float4*)so;
#pragma unroll
    for (int i = t; i < OUT_FLOATS_PER_BLOCK / 4; i += 256) {
        outv[i] = sov[i];
    }
}

extern "C" void kernel_launch(void* const* d_in, const int* in_sizes, int n_in,
                              void* d_out, int out_size, void* d_ws, size_t ws_size,
                              hipStream_t stream) {
    const float* x = (const float*)d_in[0];   // 27 floats
    const float* w = (const float*)d_in[1];   // 2048*2048*3 floats
    float* out = (float*)d_out;               // 2048*2048*9 floats

    const int pairs = 2048 * 2048;            // 4,194,304
    const int blocks = pairs / PAIRS_PER_BLOCK; // 16384, exact cover
    gf_kernel<<<blocks, 256, 0, stream>>>(x, w, out);
}